// Round 13
// baseline (515.513 us; speedup 1.0000x reference)
//
#include <hip/hip_runtime.h>
#include <math.h>

// ---------------------------------------------------------------------------
// BayesianAttention (B=8, L=512, D=1024, H=16, DK=DV=64, k_weibull=0.5)
// Numerics plan:
//   - Q/K projections + QK^T: split-bf16 (hi/lo) 3-MFMA => ~fp32-ish precision
//   - V projection, prior MLP, PV, output GEMM: plain bf16 MFMA
//   - attention (R13): split-KV, 2 halves per (bh,q-chunk) -> 8192-wave
//     parallelism (was 4096, the 50% occupancy cap):
//       k_attnA:  QK 4 k-tiles + G chain -> fp16 GS spill; partial (M1,Z1)
//       k_mergeC: logsumexp-merge halves -> C (row constant)
//       k_attnB:  K-restage + QK recompute (4 tiles) + chain + partial
//                 softmax-2 / PV / S1 -> f32 partials (33MB)
//       k_comb:   flash-combine halves -> HOB (bf16)
//   - pass-B chain trans 3->2: lp = m0+log1p(z) (EXACT logsumexp identity,
//     m0=max(s,-46.0517), z=e^-|s+46.0517|); exp(wv-nm)=e^{m0-G-nm}(1+z);
//     online max on quasi-value +ln2 margin; S1 log1p via 2-term poly
//     (dKL ~ 9e-7).
//   - lgamma 4-trans: fused log via rcp+select; 1/(12y) dropped (row-constant
//     part cancels in softmax; residual variation +-0.006).
//   - KL: kl_mean = (-S1 + L*T2 + S2)/ (B*H*L*L), S2 = B*H*L exactly.
// ---------------------------------------------------------------------------

typedef __bf16 bh_t;
typedef bh_t  bh8  __attribute__((ext_vector_type(8)));
typedef float f32x4 __attribute__((ext_vector_type(4)));
typedef _Float16 hf_t;
typedef hf_t  hf4  __attribute__((ext_vector_type(4)));

#define MFMA_BF16 __builtin_amdgcn_mfma_f32_16x16x32_bf16

// ---- scratch layout in a device-global arena (no dependence on ws_size) ----
static constexpr size_t PE = 4096ull*1024ull;        // elements in a [4096][1024] plane
static constexpr size_t P2 = PE*2ull;                // bytes of a bf16 plane
static constexpr size_t W2 = 1024ull*1024ull*2ull;   // bf16 [1024][1024] plane
static constexpr size_t O_QHI = 0;                   // Q hi/lo, K hi/lo contiguous
static constexpr size_t O_QLO = O_QHI + P2;
static constexpr size_t O_KHI = O_QLO + P2;
static constexpr size_t O_KLO = O_KHI + P2;
static constexpr size_t O_VT  = O_KLO + P2;          // bf16 [128][64][512] V^T
static constexpr size_t O_WQH = O_VT  + P2;          // 4x {hi,lo} contiguous
static constexpr size_t O_WQL = O_WQH + W2;
static constexpr size_t O_WKH = O_WQL + W2;
static constexpr size_t O_WKL = O_WKH + W2;
static constexpr size_t O_WVH = O_WKL + W2;
static constexpr size_t O_WVL = O_WVH + W2;
static constexpr size_t O_WOH = O_WVL + W2;
static constexpr size_t O_WOL = O_WOH + W2;
static constexpr size_t O_WP1H = O_WOL + W2;
static constexpr size_t O_WP1L = O_WP1H + 1024ull*64ull*2ull;
static constexpr size_t O_DG   = O_WP1L + 1024ull*64ull*2ull;
static constexpr size_t O_ALPHA= O_DG + 65536ull*4ull;
static constexpr size_t O_HO   = O_ALPHA + 65536ull*4ull;               // bf16 [4096][1024]
static constexpr size_t O_GS   = O_HO + P2;                             // fp16 G spill, 64 MB
static constexpr size_t O_ACC  = O_GS + 512ull*65536ull*2ull;           // 3 doubles
static constexpr size_t O_AQH  = O_ACC + 256;        // pre-split A planes
static constexpr size_t O_PS   = O_AQH + 5ull*P2;    // f32 [1024][128][2] partial M1/Z1
static constexpr size_t O_CB   = O_PS + 1024ull*128ull*2ull*4ull;   // f32 [512][128] C
static constexpr size_t O_MZ   = O_CB + 512ull*128ull*4ull;         // f32 [1024][128][2]
static constexpr size_t O_OP   = O_MZ + 1024ull*128ull*2ull*4ull;   // f32 [1024][128][64]
static constexpr size_t WS_TOTAL = O_OP + 1024ull*128ull*64ull*4ull;

__device__ __align__(256) unsigned char g_ws[WS_TOTAL];

// ---------------------------------------------------------------------------
// slim lgamma: reflection + shift-to-(>=4) + Stirling, 4 hw-trans total.
// 1/(12y) correction dropped: its row-constant part cancels in softmax
// (G enters as lp-G; constant shifts renormalize); residual variation 0.006.
__device__ __forceinline__ float lgamma_fast(float x)
{
    float ax = (x < 0.5f) ? (1.0f - x) : x;          // ax >= 0.5
    bool  sm = ax < 4.0f;
    float p  = sm ? ax*(ax+1.f)*(ax+2.f)*(ax+3.f) : 1.0f;
    float y  = sm ? (ax + 4.0f) : ax;                // y >= 4
    float ly = __logf(y);                            // T1
    float stir = fmaf(y - 0.5f, ly, -y) + 0.91893853320467274f;
    float r  = x - rintf(x);                         // |r| <= 0.5
    float sp = __sinf(3.14159265358979f * r);        // T2
    bool  rf = x < 0.5f;
    // non-reflect: stir - log(p) ; reflect: (lnpi - stir) + log(p/|sp|)
    float rarg = rf ? fabsf(sp) : p;
    float rnum = rf ? p : 1.0f;
    float lA = __logf(rnum * __builtin_amdgcn_rcpf(rarg));   // T3 (rcp), T4 (log)
    return (rf ? (1.14472988584940017f - stir) : stir) + lA;
}

// ---------------------------------------------------------------------------
// transpose f32 [rows][cols] -> bf16 hi/lo [cols][rows] (single matrix)
__global__ __launch_bounds__(256) void k_transpose_split(
    const float* __restrict__ in, bh_t* __restrict__ oh, bh_t* __restrict__ ol,
    int rows, int cols)
{
    __shared__ float tile[64][65];
    const int bc = blockIdx.x * 64, br = blockIdx.y * 64;
    const int t = threadIdx.x;
    const int r = t >> 2, c0 = (t & 3) * 16;
#pragma unroll
    for (int i = 0; i < 16; i += 4) {
        float4 v = *(const float4*)(in + (size_t)(br + r) * cols + bc + c0 + i);
        tile[r][c0+i]   = v.x; tile[r][c0+i+1] = v.y;
        tile[r][c0+i+2] = v.z; tile[r][c0+i+3] = v.w;
    }
    __syncthreads();
    bh8 hv[2], lv[2];
#pragma unroll
    for (int i = 0; i < 16; i++) {
        float x = tile[c0 + i][r];
        bh_t hh = (bh_t)x;
        hv[i >> 3][i & 7] = hh;
        lv[i >> 3][i & 7] = (bh_t)(x - (float)hh);
    }
    size_t ob = (size_t)(bc + r) * rows + br + c0;
    *(bh8*)(oh + ob)     = hv[0];
    *(bh8*)(oh + ob + 8) = hv[1];
    *(bh8*)(ol + ob)     = lv[0];
    *(bh8*)(ol + ob + 8) = lv[1];
}

// fused: transpose+split all four 1024x1024 weights; zeroes ACC doubles.
__global__ __launch_bounds__(256) void k_transpose_split4(
    const float* __restrict__ W0, const float* __restrict__ W1,
    const float* __restrict__ W2_, const float* __restrict__ W3,
    bh_t* __restrict__ OH, double* __restrict__ acc)
{
    __shared__ float tile[64][65];
    const int z = blockIdx.z;
    if (z == 0 && blockIdx.x == 0 && blockIdx.y == 0 && threadIdx.x < 4)
        acc[threadIdx.x] = 0.0;
    const float* in = (z == 0) ? W0 : (z == 1) ? W1 : (z == 2) ? W2_ : W3;
    bh_t* oh = OH + (size_t)z * 2ull * 1024ull * 1024ull;
    bh_t* ol = oh + 1024ull * 1024ull;
    const int bc = blockIdx.x * 64, br = blockIdx.y * 64;
    const int t = threadIdx.x;
    const int r = t >> 2, c0 = (t & 3) * 16;
#pragma unroll
    for (int i = 0; i < 16; i += 4) {
        float4 v = *(const float4*)(in + (size_t)(br + r) * 1024 + bc + c0 + i);
        tile[r][c0+i]   = v.x; tile[r][c0+i+1] = v.y;
        tile[r][c0+i+2] = v.z; tile[r][c0+i+3] = v.w;
    }
    __syncthreads();
    bh8 hv[2], lv[2];
#pragma unroll
    for (int i = 0; i < 16; i++) {
        float x = tile[c0 + i][r];
        bh_t hh = (bh_t)x;
        hv[i >> 3][i & 7] = hh;
        lv[i >> 3][i & 7] = (bh_t)(x - (float)hh);
    }
    size_t ob = (size_t)(bc + r) * 1024 + br + c0;
    *(bh8*)(oh + ob)     = hv[0];
    *(bh8*)(oh + ob + 8) = hv[1];
    *(bh8*)(ol + ob)     = lv[0];
    *(bh8*)(ol + ob + 8) = lv[1];
}

// pre-split activations: z=0 queries -> AQH/AQL, z=1 keys -> AKH/AKL,
// z=2 values -> AVH (plain bf16). Row-major [4096][1024] planes.
__global__ __launch_bounds__(256) void k_splitA(
    const float* __restrict__ q, const float* __restrict__ k,
    const float* __restrict__ v, bh_t* __restrict__ dst)
{
    const int z = blockIdx.y;
    const float* in = (z == 0) ? q : (z == 1) ? k : v;
    size_t idx = ((size_t)blockIdx.x * 256 + threadIdx.x) * 8;
    float4 v0 = *(const float4*)(in + idx);
    float4 v1 = *(const float4*)(in + idx + 4);
    float xs[8] = {v0.x, v0.y, v0.z, v0.w, v1.x, v1.y, v1.z, v1.w};
    bh8 h, l;
#pragma unroll
    for (int i = 0; i < 8; i++) {
        bh_t hh = (bh_t)xs[i];
        h[i] = hh;
        l[i] = (bh_t)(xs[i] - (float)hh);
    }
    if (z < 2) {
        bh_t* hp = dst + (size_t)z * 2 * PE;
        *(bh8*)(hp + idx)      = h;
        *(bh8*)(hp + PE + idx) = l;
    } else {
        *(bh8*)(dst + 4 * PE + idx) = h;
    }
}

// ---------------------------------------------------------------------------
// GEMM body: C[128x128 tile] = A[4096][1024](bf16 planes) @ W^T + bias.
template<bool SPLIT, int OMODE>
__device__ __forceinline__ void gemm_body(
    const bh_t* __restrict__ ABH, const bh_t* __restrict__ ABL,
    const bh_t* __restrict__ WH, const bh_t* __restrict__ WL,
    const float* __restrict__ bias,
    bh_t* __restrict__ oh, bh_t* __restrict__ ol, float* __restrict__ of,
    int n0, int m0)
{
    __shared__ __align__(16) bh_t Ah[128][40];
    __shared__ __align__(16) bh_t Al[128][40];
    __shared__ __align__(16) bh_t Bh[128][40];
    __shared__ __align__(16) bh_t Bl[128][40];
    const int t = threadIdx.x;
    const int lane = t & 63, w = t >> 6;
    const int lr = lane & 15, kg = lane >> 4;
    const int wm = (w & 1) * 64, wn = (w >> 1) * 64;
    const int ar = t >> 2, ac = (t & 3) * 8;
    f32x4 acc[4][4] = {};

    for (int kt = 0; kt < 1024; kt += 32) {
        __syncthreads();
        {
            size_t a0 = (size_t)(m0 + ar) * 1024 + kt + ac;
            size_t a1 = (size_t)(m0 + ar + 64) * 1024 + kt + ac;
            *(bh8*)&Ah[ar][ac]      = *(const bh8*)(ABH + a0);
            *(bh8*)&Ah[ar + 64][ac] = *(const bh8*)(ABH + a1);
            if constexpr (SPLIT) {
                *(bh8*)&Al[ar][ac]      = *(const bh8*)(ABL + a0);
                *(bh8*)&Al[ar + 64][ac] = *(const bh8*)(ABL + a1);
            }
            size_t b0 = (size_t)(n0 + ar) * 1024 + kt + ac;
            size_t b1 = (size_t)(n0 + ar + 64) * 1024 + kt + ac;
            *(bh8*)&Bh[ar][ac]      = *(const bh8*)(WH + b0);
            *(bh8*)&Bh[ar + 64][ac] = *(const bh8*)(WH + b1);
            if constexpr (SPLIT) {
                *(bh8*)&Bl[ar][ac]      = *(const bh8*)(WL + b0);
                *(bh8*)&Bl[ar + 64][ac] = *(const bh8*)(WL + b1);
            }
        }
        __syncthreads();
        bh8 bfh[4], bfl[4];
#pragma unroll
        for (int fn = 0; fn < 4; fn++) {
            bfh[fn] = *(bh8*)&Bh[wn + fn*16 + lr][kg * 8];
            if constexpr (SPLIT) bfl[fn] = *(bh8*)&Bl[wn + fn*16 + lr][kg * 8];
        }
#pragma unroll
        for (int fm = 0; fm < 4; fm++) {
            bh8 a_h = *(bh8*)&Ah[wm + fm*16 + lr][kg * 8];
            bh8 a_l;
            if constexpr (SPLIT) a_l = *(bh8*)&Al[wm + fm*16 + lr][kg * 8];
#pragma unroll
            for (int fn = 0; fn < 4; fn++) {
                acc[fm][fn] = MFMA_BF16(a_h, bfh[fn], acc[fm][fn], 0, 0, 0);
                if constexpr (SPLIT) {
                    acc[fm][fn] = MFMA_BF16(a_h, bfl[fn], acc[fm][fn], 0, 0, 0);
                    acc[fm][fn] = MFMA_BF16(a_l, bfh[fn], acc[fm][fn], 0, 0, 0);
                }
            }
        }
    }
#pragma unroll
    for (int fm = 0; fm < 4; fm++)
#pragma unroll
    for (int fn = 0; fn < 4; fn++) {
        int col = n0 + wn + fn*16 + lr;
        float bv = bias[col];
#pragma unroll
        for (int r = 0; r < 4; r++) {
            int row = m0 + wm + fm*16 + kg*4 + r;
            float c = acc[fm][fn][r] + bv;
            size_t idx = (size_t)row * 1024 + col;
            if constexpr (OMODE == 0) {
                bh_t hh = (bh_t)c;
                oh[idx] = hh;
                ol[idx] = (bh_t)(c - (float)hh);
            } else if constexpr (OMODE == 1) {
                oh[idx] = (bh_t)c;
            } else if constexpr (OMODE == 2) {
                of[idx] = c;
            } else {
                // VT layout: [(b*16+h)*64+dv][l], h=col>>6, dv=col&63
                int bb = row >> 9, ll = row & 511;
                oh[(((size_t)(bb*16 + (col >> 6)) * 64) + (col & 63)) * 512 + ll] = (bh_t)c;
            }
        }
    }
}

// plain GEMM wrapper (V-projection OMODE 3, output GEMM OMODE 2 + KL fold)
template<int OMODE>
__global__ __launch_bounds__(256) void k_gemm(
    const bh_t* __restrict__ ABH,
    const bh_t* __restrict__ WH, const bh_t* __restrict__ WL,
    const float* __restrict__ bias,
    bh_t* __restrict__ oh, float* __restrict__ of,
    const double* __restrict__ acc)
{
    gemm_body<false, OMODE>(ABH, nullptr, WH, WL, bias, oh, nullptr, of,
                            blockIdx.x * 128, blockIdx.y * 128);
    if constexpr (OMODE == 2) {
        if (blockIdx.x == 0 && blockIdx.y == 0 && threadIdx.x == 0) {
            // S2 = sum(exp(log(softmax+1e-20))) = B*H*L exactly
            double kl = (-acc[0] + 512.0 * acc[2] + 65536.0) / 33554432.0;
            of[4194304] = (float)kl;
        }
    }
}

// fused Q+K split projections: z selects planes (A, W, bias, out contiguous)
__global__ __launch_bounds__(256) void k_gemm_qk(
    const bh_t* __restrict__ Abase, const bh_t* __restrict__ Wbase,
    const float* __restrict__ bq, const float* __restrict__ bk,
    bh_t* __restrict__ Obase)
{
    const int z = blockIdx.z;
    const bh_t* AH = Abase + (size_t)z * 2 * PE;
    const bh_t* WH = Wbase + (size_t)z * 2ull * 1024ull * 1024ull;
    bh_t* oh = Obase + (size_t)z * 2 * PE;
    gemm_body<true, 0>(AH, AH + PE, WH, WH + 1024ull*1024ull,
                       z ? bk : bq, oh, oh + PE, nullptr,
                       blockIdx.x * 128, blockIdx.y * 128);
}

// dot_gamma[b,h,l] = Wp2 . leakyrelu(K_head[b,h,l,:] @ Wp1 + bp1) + bp2
__global__ __launch_bounds__(256) void k_prior(
    const bh_t* __restrict__ KH, const bh_t* __restrict__ WP1T,
    const float* __restrict__ bp1, const float* __restrict__ wp2,
    const float* __restrict__ bp2, float* __restrict__ DG)
{
    __shared__ __align__(16) bh_t Kt[64][72];
    __shared__ __align__(16) bh_t Wt[64][72];
    const int lt = blockIdx.x, h = blockIdx.y, b = blockIdx.z;
    const int t = threadIdx.x, lane = t & 63, w = t >> 6;
    const int lr = lane & 15, kg = lane >> 4;
    {
        int r = t >> 2, j0 = (t & 3) * 16;
        const bh_t* src = KH + ((size_t)(b*512 + lt*64 + r)) * 1024 + h*64 + j0;
        *(bh8*)&Kt[r][j0]     = *(const bh8*)src;
        *(bh8*)&Kt[r][j0 + 8] = *(const bh8*)(src + 8);
    }
    __syncthreads();
    bh8 af0 = *(bh8*)&Kt[w*16 + lr][kg * 8];
    bh8 af1 = *(bh8*)&Kt[w*16 + lr][32 + kg * 8];
    float dgp[4] = {0.f, 0.f, 0.f, 0.f};
    for (int dt = 0; dt < 16; dt++) {
        __syncthreads();
        {
            int r = t >> 2, j0 = (t & 3) * 16;
            const bh_t* src = WP1T + (size_t)(dt*64 + r) * 64 + j0;
            *(bh8*)&Wt[r][j0]     = *(const bh8*)src;
            *(bh8*)&Wt[r][j0 + 8] = *(const bh8*)(src + 8);
        }
        __syncthreads();
#pragma unroll
        for (int fn = 0; fn < 4; fn++) {
            bh8 b0 = *(bh8*)&Wt[fn*16 + lr][kg * 8];
            bh8 b1 = *(bh8*)&Wt[fn*16 + lr][32 + kg * 8];
            f32x4 acc = {};
            acc = MFMA_BF16(af0, b0, acc, 0, 0, 0);
            acc = MFMA_BF16(af1, b1, acc, 0, 0, 0);
            int d = dt*64 + fn*16 + lr;
            float bpv = bp1[d], wvv = wp2[d];
#pragma unroll
            for (int r = 0; r < 4; r++) {
                float hv = acc[r] + bpv;
                hv = (hv >= 0.f) ? hv : 0.01f * hv;
                dgp[r] = fmaf(hv, wvv, dgp[r]);
            }
        }
    }
#pragma unroll
    for (int r = 0; r < 4; r++) {
        float v = dgp[r];
        v += __shfl_xor(v, 1); v += __shfl_xor(v, 2);
        v += __shfl_xor(v, 4); v += __shfl_xor(v, 8);
        dgp[r] = v;
    }
    if (lr == 0) {
        float b2 = bp2[0];
        int bh = b * 16 + h;
#pragma unroll
        for (int r = 0; r < 4; r++)
            DG[(size_t)bh*512 + lt*64 + w*16 + kg*4 + r] = dgp[r] + b2;
    }
}

// alpha = softmax_k(dot_gamma); accumulate alpha-only KL terms into acc[2]
__global__ __launch_bounds__(512) void k_alpha(
    const float* __restrict__ DG, float* __restrict__ AL, double* __restrict__ acc)
{
    __shared__ float red[512];
    const int bh = blockIdx.x, t = threadIdx.x;
    float v = DG[(size_t)bh * 512 + t];
    red[t] = v; __syncthreads();
    for (int s = 256; s > 0; s >>= 1) { if (t < s) red[t] = fmaxf(red[t], red[t+s]); __syncthreads(); }
    float m = red[0]; __syncthreads();
    float e = expf(v - m);
    red[t] = e; __syncthreads();
    for (int s = 256; s > 0; s >>= 1) { if (t < s) red[t] += red[t+s]; __syncthreads(); }
    float ssum = red[0]; __syncthreads();
    float a = e / ssum;                 // * BETA_GAMMA (=1)
    AL[(size_t)bh * 512 + t] = a;
    // lg1 + 2*eulergamma
    float t2 = a * 1.8475785103630112f + lgammaf(a + 1e-20f);
    red[t] = t2; __syncthreads();
    for (int s = 256; s > 0; s >>= 1) { if (t < s) red[t] += red[t+s]; __syncthreads(); }
    if (t == 0) atomicAdd(&acc[2], (double)red[0]);
}

// ---------------------------------------------------------------------------
// split-KV attention, stage A: QK split-MFMA over 4 k-tiles + G chain ->
// fp16 GS spill; partial (M1, Z1) -> PS. 1024 blocks (2 halves x 512).
__global__ __launch_bounds__(512, 8) void k_attnA(
    const bh_t* __restrict__ QH, const bh_t* __restrict__ QL,
    const bh_t* __restrict__ KH, const bh_t* __restrict__ KL,
    const float* __restrict__ U, hf_t* __restrict__ GS,
    float* __restrict__ PS)
{
    __shared__ __align__(16) bh_t KtH[64][72];
    __shared__ __align__(16) bh_t KtL[64][72];

    const int bid = blockIdx.x;
    const int split = bid >> 9, flat = bid & 511;
    const int bh = flat & 127, qc = flat >> 7;
    const int b = bh >> 4, h = bh & 15;
    const int t = threadIdx.x, w = t >> 6, lane = t & 63;
    const int lr = lane & 15, kg = lane >> 4;
    const int q0 = qc * 128 + w * 16;
    const int sr = t >> 3, sj = (t & 7) * 8;
    const float* Up = U + ((size_t)bh * 512 + q0 + kg * 4) * 512;
    hf_t* GSp = GS + (size_t)flat * 65536 + (size_t)w * 8192;

    bh8 qh[2], ql[2];
    {
        size_t qb = ((size_t)(b * 512) + q0 + lr) * 1024 + h * 64;
        qh[0] = *(const bh8*)(QH + qb + kg * 8);
        qh[1] = *(const bh8*)(QH + qb + 32 + kg * 8);
        ql[0] = *(const bh8*)(QL + qb + kg * 8);
        ql[1] = *(const bh8*)(QL + qb + 32 + kg * 8);
    }
    float M1[4], Z1[4];
#pragma unroll
    for (int r = 0; r < 4; r++) { M1[r] = -INFINITY; Z1[r] = 0.f; }

    for (int kt = split * 4; kt < split * 4 + 4; kt++) {
        __syncthreads();
        {
            size_t src = ((size_t)(b*512 + kt*64 + sr)) * 1024 + h*64 + sj;
            *(bh8*)&KtH[sr][sj] = *(const bh8*)(KH + src);
            *(bh8*)&KtL[sr][sj] = *(const bh8*)(KL + src);
        }
        __syncthreads();
        f32x4 av[4];
#pragma unroll
        for (int fn = 0; fn < 4; fn++) {
            f32x4 a = {};
#pragma unroll
            for (int ks = 0; ks < 2; ks++) {
                bh8 kb  = *(bh8*)&KtH[fn*16 + lr][ks*32 + kg*8];
                bh8 kl2 = *(bh8*)&KtL[fn*16 + lr][ks*32 + kg*8];
                a = MFMA_BF16(qh[ks], kb,  a, 0, 0, 0);
                a = MFMA_BF16(qh[ks], kl2, a, 0, 0, 0);
                a = MFMA_BF16(ql[ks], kb,  a, 0, 0, 0);
            }
#pragma unroll
            for (int r = 0; r < 4; r++) a[r] *= 8.0f;   // att / SCALE, SCALE=1/8
            av[fn] = a;
            // Gumbel/lgamma chain fills MFMA latency; spill G fp16.
            int k = kt * 64 + fn * 16 + lr;
            hf4 gh;
#pragma unroll
            for (int r = 0; r < 4; r++) {
                float u  = Up[(size_t)r * 512 + k];
                float tt = (1.0f - u) + 1e-20f;
                float gl = 1e-20f - __logf(tt);
                float g  = __logf(gl);
                gh[r] = (hf_t)lgamma_fast(fmaf(2.0f, g, 3.0f));
            }
            *(hf4*)(GSp + ((size_t)(kt*4 + fn) * 64 + lane) * 4) = gh;
        }
#pragma unroll
        for (int r = 0; r < 4; r++) {
            float mx = fmaxf(fmaxf(av[0][r], av[1][r]), fmaxf(av[2][r], av[3][r]));
            mx = fmaxf(mx, __shfl_xor(mx, 1));
            mx = fmaxf(mx, __shfl_xor(mx, 2));
            mx = fmaxf(mx, __shfl_xor(mx, 4));
            mx = fmaxf(mx, __shfl_xor(mx, 8));
            float nm = fmaxf(M1[r], mx);
            float es = __expf(av[0][r]-nm) + __expf(av[1][r]-nm)
                     + __expf(av[2][r]-nm) + __expf(av[3][r]-nm);
            es += __shfl_xor(es, 1); es += __shfl_xor(es, 2);
            es += __shfl_xor(es, 4); es += __shfl_xor(es, 8);
            Z1[r] = Z1[r] * __expf(M1[r] - nm) + es;
            M1[r] = nm;
        }
    }
    if (lr == 0) {
#pragma unroll
        for (int r = 0; r < 4; r++) {
            size_t row = (size_t)bid * 128 + (w*16 + kg*4 + r);
            PS[row * 2]     = M1[r];
            PS[row * 2 + 1] = Z1[r];
        }
    }
}

// merge halves' (M1,Z1) -> C = logsumexp (row constant)
__global__ __launch_bounds__(512) void k_mergeC(
    const float* __restrict__ PS, float* __restrict__ CB)
{
    int idx = blockIdx.x * 512 + threadIdx.x;          // row in [0, 65536)
    float Ma = PS[(size_t)idx * 2],           Za = PS[(size_t)idx * 2 + 1];
    float Mb = PS[(size_t)(65536 + idx) * 2], Zb = PS[(size_t)(65536 + idx) * 2 + 1];
    float M = fmaxf(Ma, Mb);
    float Z = Za * __expf(Ma - M) + Zb * __expf(Mb - M);
    CB[idx] = M + __logf(Z);
}

// split-KV attention, stage B: K-restage + QK recompute over 4 k-tiles +
// lp/G chain (2-trans logsumexp form) + partial softmax-2/PV/S1.
__global__ __launch_bounds__(512, 6) void k_attnB(
    const bh_t* __restrict__ QH, const bh_t* __restrict__ QL,
    const bh_t* __restrict__ KH, const bh_t* __restrict__ KL,
    const bh_t* __restrict__ VT, const float* __restrict__ AL,
    const hf_t* __restrict__ GS, const float* __restrict__ CB,
    float* __restrict__ OP, float* __restrict__ MZ,
    double* __restrict__ acc)
{
    __shared__ __align__(16) bh_t KtH[64][72];
    __shared__ __align__(16) bh_t KtL[64][72];
    __shared__ __align__(16) bh_t Vt[64][72];
    __shared__ __align__(16) bh_t Sl[8][16][72];
    __shared__ float Asm[64];
    __shared__ float red[512];

    const int bid = blockIdx.x;
    const int split = bid >> 9, flat = bid & 511;
    const int bh = flat & 127, qc = flat >> 7;
    const int b = bh >> 4, h = bh & 15;
    const int t = threadIdx.x, w = t >> 6, lane = t & 63;
    const int lr = lane & 15, kg = lane >> 4;
    const int q0 = qc * 128 + w * 16;
    const int sr = t >> 3, sj = (t & 7) * 8;
    const hf_t* GSp = GS + (size_t)flat * 65536 + (size_t)w * 8192;

    bh8 qh[2], ql[2];
    {
        size_t qb = ((size_t)(b * 512) + q0 + lr) * 1024 + h * 64;
        qh[0] = *(const bh8*)(QH + qb + kg * 8);
        qh[1] = *(const bh8*)(QH + qb + 32 + kg * 8);
        ql[0] = *(const bh8*)(QL + qb + kg * 8);
        ql[1] = *(const bh8*)(QL + qb + 32 + kg * 8);
    }
    float C4[4];
#pragma unroll
    for (int r = 0; r < 4; r++)
        C4[r] = CB[flat * 128 + w*16 + kg*4 + r];

    float M2[4], Z2[4];
    f32x4 oacc[4] = {};
#pragma unroll
    for (int r = 0; r < 4; r++) { M2[r] = -INFINITY; Z2[r] = 0.f; }
    float S1f = 0.f;
    const float LEPS = 46.0517019f;   // -log(1e-20)

    for (int kt = split * 4; kt < split * 4 + 4; kt++) {
        __syncthreads();
        {   // stage K hi/lo + V^T tile + alpha tile
            size_t src = ((size_t)(b*512 + kt*64 + sr)) * 1024 + h*64 + sj;
            *(bh8*)&KtH[sr][sj] = *(const bh8*)(KH + src);
            *(bh8*)&KtL[sr][sj] = *(const bh8*)(KL + src);
            const bh_t* vsrc = VT + ((size_t)bh * 64 + sr) * 512 + kt*64 + sj;
            *(bh8*)&Vt[sr][sj] = *(const bh8*)vsrc;
            if (t < 64) Asm[t] = AL[(size_t)bh * 512 + kt * 64 + t];
        }
        __syncthreads();
        f32x4 wv[4], zq[4];
#pragma unroll
        for (int fn = 0; fn < 4; fn++) {
            f32x4 a = {};
#pragma unroll
            for (int ks = 0; ks < 2; ks++) {
                bh8 kb  = *(bh8*)&KtH[fn*16 + lr][ks*32 + kg*8];
                bh8 kl2 = *(bh8*)&KtL[fn*16 + lr][ks*32 + kg*8];
                a = MFMA_BF16(qh[ks], kb,  a, 0, 0, 0);
                a = MFMA_BF16(qh[ks], kl2, a, 0, 0, 0);
                a = MFMA_BF16(ql[ks], kb,  a, 0, 0, 0);
            }
            hf4 gh = *(const hf4*)(GSp + ((size_t)(kt*4 + fn) * 64 + lane) * 4);
            float alv = Asm[fn * 16 + lr];
#pragma unroll
            for (int r = 0; r < 4; r++) {
                float s  = fmaf(a[r], 8.0f, -C4[r]);      // logit - C
                // lp = logsumexp(s, -46.0517) = m0 + log1p(z) (EXACT identity)
                float m0 = fmaxf(s, -LEPS);
                float d  = fabsf(s + LEPS);
                float z  = __expf(-d);
                zq[fn][r] = z;
                // S1: log1p(z) ~= z - z^2/2  (dKL ~ 1e-6)
                S1f = fmaf(alv, m0 + z * fmaf(-0.5f, z, 1.0f), S1f);
                wv[fn][r] = m0 - (float)gh[r];            // quasi-wv (true = +log1p(z))
            }
        }
#pragma unroll
        for (int r = 0; r < 4; r++) {
            float mx = fmaxf(fmaxf(wv[0][r], wv[1][r]), fmaxf(wv[2][r], wv[3][r]));
            mx = fmaxf(mx, __shfl_xor(mx, 1));
            mx = fmaxf(mx, __shfl_xor(mx, 2));
            mx = fmaxf(mx, __shfl_xor(mx, 4));
            mx = fmaxf(mx, __shfl_xor(mx, 8));
            float nm = fmaxf(M2[r], mx + 0.6931472f);    // bound >= all true wv
            float sc = __expf(M2[r] - nm);               // exp(-inf)=0
            float zs = 0.f;
#pragma unroll
            for (int fn = 0; fn < 4; fn++) {
                // exp(true_wv - nm) = exp(quasi - nm) * (1+z)  (exact)
                float sv = __expf(wv[fn][r] - nm) * (1.0f + zq[fn][r]);
                zs += sv;
                Sl[w][kg * 4 + r][fn * 16 + lr] = (bh_t)sv;
            }
            zs += __shfl_xor(zs, 1); zs += __shfl_xor(zs, 2);
            zs += __shfl_xor(zs, 4); zs += __shfl_xor(zs, 8);
            Z2[r] = fmaf(Z2[r], sc, zs);
            M2[r] = nm;
#pragma unroll
            for (int fo = 0; fo < 4; fo++) oacc[fo][r] *= sc;
        }
        // Sl slice per-wave (program-ordered); Vt/Kt rewritten after barrier.
        bh8 sa0 = *(bh8*)&Sl[w][lr][kg*8];
        bh8 sa1 = *(bh8*)&Sl[w][lr][32 + kg*8];
#pragma unroll
        for (int fo = 0; fo < 4; fo++) {
            bh8 v0 = *(bh8*)&Vt[fo*16 + lr][kg*8];
            bh8 v1 = *(bh8*)&Vt[fo*16 + lr][32 + kg*8];
            oacc[fo] = MFMA_BF16(sa0, v0, oacc[fo], 0, 0, 0);
            oacc[fo] = MFMA_BF16(sa1, v1, oacc[fo], 0, 0, 0);
        }
    }
    // write raw partials (no normalization; k_comb merges)
#pragma unroll
    for (int fo = 0; fo < 4; fo++) {
#pragma unroll
        for (int r = 0; r < 4; r++) {
            size_t row = (size_t)bid * 128 + (w*16 + kg*4 + r);
            OP[row * 64 + (fo*16 + lr)] = oacc[fo][r];
        }
    }
    if (lr == 0) {
#pragma unroll
        for (int r = 0; r < 4; r++) {
            size_t row = (size_t)bid * 128 + (w*16 + kg*4 + r);
            MZ[row * 2]     = M2[r];
            MZ[row * 2 + 1] = Z2[r];
        }
    }
    red[t] = S1f; __syncthreads();
    for (int s = 256; s > 0; s >>= 1) { if (t < s) red[t] += red[t+s]; __syncthreads(); }
    if (t == 0) atomicAdd(&acc[0], (double)red[0]);
}

// flash-combine the two KV halves -> HOB (bf16)
__global__ __launch_bounds__(256) void k_comb(
    const float* __restrict__ OP, const float* __restrict__ MZ,
    bh_t* __restrict__ HOB)
{
    size_t idx = (size_t)blockIdx.x * 256 + threadIdx.x;  // [0, 4194304)
    int dv = idx & 63;
    int rowg = (int)(idx >> 6);                           // [0, 65536)
    float Ma = MZ[(size_t)rowg * 2],             Za = MZ[(size_t)rowg * 2 + 1];
    float Mb = MZ[(size_t)(65536 + rowg) * 2],   Zb = MZ[(size_t)(65536 + rowg) * 2 + 1];
    float M  = fmaxf(Ma, Mb);
    float wa = __expf(Ma - M), wb = __expf(Mb - M);
    float Z  = Za * wa + Zb * wb;
    float o  = OP[(size_t)rowg * 64 + dv] * wa
             + OP[(size_t)(65536 + rowg) * 64 + dv] * wb;
    int flat = rowg >> 7, rl = rowg & 127;
    int bh = flat & 127, qc = flat >> 7;
    int b = bh >> 4, h = bh & 15;
    int q = qc * 128 + rl;
    HOB[((size_t)(b * 512 + q)) * 1024 + h * 64 + dv] = (bh_t)(o / Z);
}

// ---------------------------------------------------------------------------
extern "C" void kernel_launch(void* const* d_in, const int* in_sizes, int n_in,
                              void* d_out, int out_size, void* d_ws, size_t ws_size,
                              hipStream_t stream)
{
    (void)in_sizes; (void)n_in; (void)d_ws; (void)ws_size; (void)out_size;
    const float* queries = (const float*)d_in[0];
    const float* keys    = (const float*)d_in[1];
    const float* values  = (const float*)d_in[2];
    const float* unif    = (const float*)d_in[3];
    const float* Wq = (const float*)d_in[4];  const float* bq = (const float*)d_in[5];
    const float* Wk = (const float*)d_in[6];  const float* bk = (const float*)d_in[7];
    const float* Wv = (const float*)d_in[8];  const float* bv = (const float*)d_in[9];
    const float* Wo = (const float*)d_in[10]; const float* bo = (const float*)d_in[11];
    const float* Wp1 = (const float*)d_in[12]; const float* bp1 = (const float*)d_in[13];
    const float* Wp2 = (const float*)d_in[14]; const float* bp2 = (const float*)d_in[15];

    unsigned char* ws = nullptr;
    hipGetSymbolAddress((void**)&ws, HIP_SYMBOL(g_ws));

    bh_t* QHI = (bh_t*)(ws + O_QHI); bh_t* QLO = (bh_t*)(ws + O_QLO);
    bh_t* KHI = (bh_t*)(ws + O_KHI); bh_t* KLO = (bh_t*)(ws + O_KLO);
    bh_t* VTp = (bh_t*)(ws + O_VT);
    bh_t* WQH = (bh_t*)(ws + O_WQH);
    bh_t* WVH = (bh_t*)(ws + O_WVH); bh_t* WVL = (bh_t*)(ws + O_WVL);
    bh_t* WOH = (bh_t*)(ws + O_WOH); bh_t* WOL = (bh_t*)(ws + O_WOL);
    bh_t* WP1H = (bh_t*)(ws + O_WP1H); bh_t* WP1L = (bh_t*)(ws + O_WP1L);
    float* DG    = (float*)(ws + O_DG);
    float* ALPHA = (float*)(ws + O_ALPHA);
    bh_t*  HOB   = (bh_t*)(ws + O_HO);
    hf_t*  GS    = (hf_t*)(ws + O_GS);
    double* ACC  = (double*)(ws + O_ACC);
    bh_t*  AQH   = (bh_t*)(ws + O_AQH);
    bh_t*  AVH   = AQH + 4 * PE;
    float* PS    = (float*)(ws + O_PS);
    float* CB    = (float*)(ws + O_CB);
    float* MZ    = (float*)(ws + O_MZ);
    float* OP    = (float*)(ws + O_OP);
    float* outF  = (float*)d_out;

    // weight transposes (+ ACC zeroing) and activation pre-split
    k_transpose_split4<<<dim3(16,16,4), 256, 0, stream>>>(Wq, Wk, Wv, Wo, WQH, ACC);
    k_transpose_split<<<dim3(16,1), 256, 0, stream>>>(Wp1, WP1H, WP1L, 64, 1024);
    k_splitA<<<dim3(2048,3), 256, 0, stream>>>(queries, keys, values, AQH);

    // Q and K split projections fused (z=2); V projection writes VT directly
    k_gemm_qk<<<dim3(8,32,2), 256, 0, stream>>>(AQH, WQH, bq, bk, QHI);
    k_gemm<3><<<dim3(8,32), 256, 0, stream>>>(AVH, WVH, WVL, bv, VTp, nullptr, nullptr);

    k_prior<<<dim3(8,16,8), 256, 0, stream>>>(KHI, WP1H, bp1, Wp2, bp2, DG);
    k_alpha<<<128, 512, 0, stream>>>(DG, ALPHA, ACC);

    // split-KV attention: A (stats+G) -> mergeC -> B (softmax-2+PV) -> combine
    k_attnA<<<1024, 512, 0, stream>>>(QHI, QLO, KHI, KLO, unif, GS, PS);
    k_mergeC<<<128, 512, 0, stream>>>(PS, CB);
    k_attnB<<<1024, 512, 0, stream>>>(QHI, QLO, KHI, KLO, VTp, ALPHA, GS, CB, OP, MZ, ACC);
    k_comb<<<16384, 256, 0, stream>>>(OP, MZ, HOB);

    // output GEMM (f32) + KL finalization folded into its epilogue
    k_gemm<2><<<dim3(8,32), 256, 0, stream>>>(HOB, WOH, WOL, bo, nullptr, outF, ACC);
}

// Round 14
// 312.665 us; speedup vs baseline: 1.6488x; 1.6488x over previous
//
#include <hip/hip_runtime.h>
#include <math.h>

// ---------------------------------------------------------------------------
// BayesianAttention (B=8, L=512, D=1024, H=16, DK=DV=64, k_weibull=0.5)
// Numerics plan:
//   - Q/K projections + QK^T: split-bf16 (hi/lo) 3-MFMA => ~fp32-ish precision
//   - V projection, prior MLP, PV, output GEMM: plain bf16 MFMA
//   - k_attn: R12 monolithic structure (proven 192us; R13 split-KV regressed
//     to memory-bound, reverted) + R13-validated transcendental cuts:
//       pass A: QK MFMA + (M1,Z1) + G chain (4-trans lgamma) -> fp16 GS spill
//       pass B: K-restage + QK recompute + 2-trans logsumexp chain
//               lp = m0 + log1p(z), m0=max(s,-46.0517), z=e^-|s+46.0517|
//               (EXACT identity); online max on quasi-value +ln2 margin;
//               exp(true_wv-nm) = exp(quasi-nm)*(1+z) exact;
//               S1 log1p via 2-term poly (dKL ~ 1e-6).
//   - lgamma 4-trans: fused log via rcp+select; 1/(12y) dropped (row-constant
//     part cancels in softmax; residual variation +-0.006, validated R13).
//   - k_gemm (R12): A pre-split once (k_splitA); 128x128 tile, 4x4 frags.
//   - KL: kl_mean = (-S1 + L*T2 + S2)/(B*H*L*L), S2 = B*H*L exactly.
// ---------------------------------------------------------------------------

typedef __bf16 bh_t;
typedef bh_t  bh8  __attribute__((ext_vector_type(8)));
typedef float f32x4 __attribute__((ext_vector_type(4)));
typedef _Float16 hf_t;
typedef hf_t  hf4  __attribute__((ext_vector_type(4)));

#define MFMA_BF16 __builtin_amdgcn_mfma_f32_16x16x32_bf16

// ---- scratch layout in a device-global arena (no dependence on ws_size) ----
static constexpr size_t PE = 4096ull*1024ull;        // elements in a [4096][1024] plane
static constexpr size_t P2 = PE*2ull;                // bytes of a bf16 plane
static constexpr size_t W2 = 1024ull*1024ull*2ull;   // bf16 [1024][1024] plane
static constexpr size_t O_QHI = 0;                   // Q hi/lo, K hi/lo contiguous
static constexpr size_t O_QLO = O_QHI + P2;
static constexpr size_t O_KHI = O_QLO + P2;
static constexpr size_t O_KLO = O_KHI + P2;
static constexpr size_t O_VT  = O_KLO + P2;          // bf16 [128][64][512] V^T
static constexpr size_t O_WQH = O_VT  + P2;          // 4x {hi,lo} contiguous
static constexpr size_t O_WQL = O_WQH + W2;
static constexpr size_t O_WKH = O_WQL + W2;
static constexpr size_t O_WKL = O_WKH + W2;
static constexpr size_t O_WVH = O_WKL + W2;
static constexpr size_t O_WVL = O_WVH + W2;
static constexpr size_t O_WOH = O_WVL + W2;
static constexpr size_t O_WOL = O_WOH + W2;
static constexpr size_t O_WP1H = O_WOL + W2;
static constexpr size_t O_WP1L = O_WP1H + 1024ull*64ull*2ull;
static constexpr size_t O_DG   = O_WP1L + 1024ull*64ull*2ull;
static constexpr size_t O_ALPHA= O_DG + 65536ull*4ull;
static constexpr size_t O_HO   = O_ALPHA + 65536ull*4ull;               // bf16 [4096][1024]
static constexpr size_t O_GS   = O_HO + P2;                             // fp16 G spill, 64 MB
static constexpr size_t O_ACC  = O_GS + 512ull*65536ull*2ull;           // 3 doubles
static constexpr size_t O_AQH  = O_ACC + 256;        // pre-split A planes:
static constexpr size_t WS_TOTAL = O_AQH + 5ull*P2;  // AQH,AQL,AKH,AKL,AVH

__device__ __align__(256) unsigned char g_ws[WS_TOTAL];

// ---------------------------------------------------------------------------
// slim lgamma: reflection + shift-to-(>=4) + Stirling, 4 hw-trans total.
// 1/(12y) dropped: row-constant part cancels in softmax; residual +-0.006
// (validated R13: absmax unchanged).
__device__ __forceinline__ float lgamma_fast(float x)
{
    float ax = (x < 0.5f) ? (1.0f - x) : x;          // ax >= 0.5
    bool  sm = ax < 4.0f;
    float p  = sm ? ax*(ax+1.f)*(ax+2.f)*(ax+3.f) : 1.0f;
    float y  = sm ? (ax + 4.0f) : ax;                // y >= 4
    float ly = __logf(y);                            // T1
    float stir = fmaf(y - 0.5f, ly, -y) + 0.91893853320467274f;
    float r  = x - rintf(x);                         // |r| <= 0.5
    float sp = __sinf(3.14159265358979f * r);        // T2
    bool  rf = x < 0.5f;
    // non-reflect: stir - log(p) ; reflect: (lnpi - stir) + log(p/|sp|)
    float rarg = rf ? fabsf(sp) : p;
    float rnum = rf ? p : 1.0f;
    float lA = __logf(rnum * __builtin_amdgcn_rcpf(rarg));   // T3 (rcp), T4 (log)
    return (rf ? (1.14472988584940017f - stir) : stir) + lA;
}

// ---------------------------------------------------------------------------
// transpose f32 [rows][cols] -> bf16 hi/lo [cols][rows] (single matrix)
__global__ __launch_bounds__(256) void k_transpose_split(
    const float* __restrict__ in, bh_t* __restrict__ oh, bh_t* __restrict__ ol,
    int rows, int cols)
{
    __shared__ float tile[64][65];
    const int bc = blockIdx.x * 64, br = blockIdx.y * 64;
    const int t = threadIdx.x;
    const int r = t >> 2, c0 = (t & 3) * 16;
#pragma unroll
    for (int i = 0; i < 16; i += 4) {
        float4 v = *(const float4*)(in + (size_t)(br + r) * cols + bc + c0 + i);
        tile[r][c0+i]   = v.x; tile[r][c0+i+1] = v.y;
        tile[r][c0+i+2] = v.z; tile[r][c0+i+3] = v.w;
    }
    __syncthreads();
    bh8 hv[2], lv[2];
#pragma unroll
    for (int i = 0; i < 16; i++) {
        float x = tile[c0 + i][r];
        bh_t hh = (bh_t)x;
        hv[i >> 3][i & 7] = hh;
        lv[i >> 3][i & 7] = (bh_t)(x - (float)hh);
    }
    size_t ob = (size_t)(bc + r) * rows + br + c0;
    *(bh8*)(oh + ob)     = hv[0];
    *(bh8*)(oh + ob + 8) = hv[1];
    *(bh8*)(ol + ob)     = lv[0];
    *(bh8*)(ol + ob + 8) = lv[1];
}

// fused: transpose+split all four 1024x1024 weights; zeroes ACC doubles.
__global__ __launch_bounds__(256) void k_transpose_split4(
    const float* __restrict__ W0, const float* __restrict__ W1,
    const float* __restrict__ W2_, const float* __restrict__ W3,
    bh_t* __restrict__ OH, double* __restrict__ acc)
{
    __shared__ float tile[64][65];
    const int z = blockIdx.z;
    if (z == 0 && blockIdx.x == 0 && blockIdx.y == 0 && threadIdx.x < 4)
        acc[threadIdx.x] = 0.0;
    const float* in = (z == 0) ? W0 : (z == 1) ? W1 : (z == 2) ? W2_ : W3;
    bh_t* oh = OH + (size_t)z * 2ull * 1024ull * 1024ull;
    bh_t* ol = oh + 1024ull * 1024ull;
    const int bc = blockIdx.x * 64, br = blockIdx.y * 64;
    const int t = threadIdx.x;
    const int r = t >> 2, c0 = (t & 3) * 16;
#pragma unroll
    for (int i = 0; i < 16; i += 4) {
        float4 v = *(const float4*)(in + (size_t)(br + r) * 1024 + bc + c0 + i);
        tile[r][c0+i]   = v.x; tile[r][c0+i+1] = v.y;
        tile[r][c0+i+2] = v.z; tile[r][c0+i+3] = v.w;
    }
    __syncthreads();
    bh8 hv[2], lv[2];
#pragma unroll
    for (int i = 0; i < 16; i++) {
        float x = tile[c0 + i][r];
        bh_t hh = (bh_t)x;
        hv[i >> 3][i & 7] = hh;
        lv[i >> 3][i & 7] = (bh_t)(x - (float)hh);
    }
    size_t ob = (size_t)(bc + r) * 1024 + br + c0;
    *(bh8*)(oh + ob)     = hv[0];
    *(bh8*)(oh + ob + 8) = hv[1];
    *(bh8*)(ol + ob)     = lv[0];
    *(bh8*)(ol + ob + 8) = lv[1];
}

// pre-split activations: z=0 queries -> AQH/AQL, z=1 keys -> AKH/AKL,
// z=2 values -> AVH (plain bf16). Row-major [4096][1024] planes.
__global__ __launch_bounds__(256) void k_splitA(
    const float* __restrict__ q, const float* __restrict__ k,
    const float* __restrict__ v, bh_t* __restrict__ dst)
{
    const int z = blockIdx.y;
    const float* in = (z == 0) ? q : (z == 1) ? k : v;
    size_t idx = ((size_t)blockIdx.x * 256 + threadIdx.x) * 8;
    float4 v0 = *(const float4*)(in + idx);
    float4 v1 = *(const float4*)(in + idx + 4);
    float xs[8] = {v0.x, v0.y, v0.z, v0.w, v1.x, v1.y, v1.z, v1.w};
    bh8 h, l;
#pragma unroll
    for (int i = 0; i < 8; i++) {
        bh_t hh = (bh_t)xs[i];
        h[i] = hh;
        l[i] = (bh_t)(xs[i] - (float)hh);
    }
    if (z < 2) {
        bh_t* hp = dst + (size_t)z * 2 * PE;
        *(bh8*)(hp + idx)      = h;
        *(bh8*)(hp + PE + idx) = l;
    } else {
        *(bh8*)(dst + 4 * PE + idx) = h;
    }
}

// ---------------------------------------------------------------------------
// GEMM body: C[128x128 tile] = A[4096][1024](bf16 planes) @ W^T + bias.
template<bool SPLIT, int OMODE>
__device__ __forceinline__ void gemm_body(
    const bh_t* __restrict__ ABH, const bh_t* __restrict__ ABL,
    const bh_t* __restrict__ WH, const bh_t* __restrict__ WL,
    const float* __restrict__ bias,
    bh_t* __restrict__ oh, bh_t* __restrict__ ol, float* __restrict__ of,
    int n0, int m0)
{
    __shared__ __align__(16) bh_t Ah[128][40];
    __shared__ __align__(16) bh_t Al[128][40];
    __shared__ __align__(16) bh_t Bh[128][40];
    __shared__ __align__(16) bh_t Bl[128][40];
    const int t = threadIdx.x;
    const int lane = t & 63, w = t >> 6;
    const int lr = lane & 15, kg = lane >> 4;
    const int wm = (w & 1) * 64, wn = (w >> 1) * 64;
    const int ar = t >> 2, ac = (t & 3) * 8;
    f32x4 acc[4][4] = {};

    for (int kt = 0; kt < 1024; kt += 32) {
        __syncthreads();
        {
            size_t a0 = (size_t)(m0 + ar) * 1024 + kt + ac;
            size_t a1 = (size_t)(m0 + ar + 64) * 1024 + kt + ac;
            *(bh8*)&Ah[ar][ac]      = *(const bh8*)(ABH + a0);
            *(bh8*)&Ah[ar + 64][ac] = *(const bh8*)(ABH + a1);
            if constexpr (SPLIT) {
                *(bh8*)&Al[ar][ac]      = *(const bh8*)(ABL + a0);
                *(bh8*)&Al[ar + 64][ac] = *(const bh8*)(ABL + a1);
            }
            size_t b0 = (size_t)(n0 + ar) * 1024 + kt + ac;
            size_t b1 = (size_t)(n0 + ar + 64) * 1024 + kt + ac;
            *(bh8*)&Bh[ar][ac]      = *(const bh8*)(WH + b0);
            *(bh8*)&Bh[ar + 64][ac] = *(const bh8*)(WH + b1);
            if constexpr (SPLIT) {
                *(bh8*)&Bl[ar][ac]      = *(const bh8*)(WL + b0);
                *(bh8*)&Bl[ar + 64][ac] = *(const bh8*)(WL + b1);
            }
        }
        __syncthreads();
        bh8 bfh[4], bfl[4];
#pragma unroll
        for (int fn = 0; fn < 4; fn++) {
            bfh[fn] = *(bh8*)&Bh[wn + fn*16 + lr][kg * 8];
            if constexpr (SPLIT) bfl[fn] = *(bh8*)&Bl[wn + fn*16 + lr][kg * 8];
        }
#pragma unroll
        for (int fm = 0; fm < 4; fm++) {
            bh8 a_h = *(bh8*)&Ah[wm + fm*16 + lr][kg * 8];
            bh8 a_l;
            if constexpr (SPLIT) a_l = *(bh8*)&Al[wm + fm*16 + lr][kg * 8];
#pragma unroll
            for (int fn = 0; fn < 4; fn++) {
                acc[fm][fn] = MFMA_BF16(a_h, bfh[fn], acc[fm][fn], 0, 0, 0);
                if constexpr (SPLIT) {
                    acc[fm][fn] = MFMA_BF16(a_h, bfl[fn], acc[fm][fn], 0, 0, 0);
                    acc[fm][fn] = MFMA_BF16(a_l, bfh[fn], acc[fm][fn], 0, 0, 0);
                }
            }
        }
    }
#pragma unroll
    for (int fm = 0; fm < 4; fm++)
#pragma unroll
    for (int fn = 0; fn < 4; fn++) {
        int col = n0 + wn + fn*16 + lr;
        float bv = bias[col];
#pragma unroll
        for (int r = 0; r < 4; r++) {
            int row = m0 + wm + fm*16 + kg*4 + r;
            float c = acc[fm][fn][r] + bv;
            size_t idx = (size_t)row * 1024 + col;
            if constexpr (OMODE == 0) {
                bh_t hh = (bh_t)c;
                oh[idx] = hh;
                ol[idx] = (bh_t)(c - (float)hh);
            } else if constexpr (OMODE == 1) {
                oh[idx] = (bh_t)c;
            } else if constexpr (OMODE == 2) {
                of[idx] = c;
            } else {
                // VT layout: [(b*16+h)*64+dv][l], h=col>>6, dv=col&63
                int bb = row >> 9, ll = row & 511;
                oh[(((size_t)(bb*16 + (col >> 6)) * 64) + (col & 63)) * 512 + ll] = (bh_t)c;
            }
        }
    }
}

// plain GEMM wrapper (V-projection OMODE 3, output GEMM OMODE 2 + KL fold)
template<int OMODE>
__global__ __launch_bounds__(256) void k_gemm(
    const bh_t* __restrict__ ABH,
    const bh_t* __restrict__ WH, const bh_t* __restrict__ WL,
    const float* __restrict__ bias,
    bh_t* __restrict__ oh, float* __restrict__ of,
    const double* __restrict__ acc)
{
    gemm_body<false, OMODE>(ABH, nullptr, WH, WL, bias, oh, nullptr, of,
                            blockIdx.x * 128, blockIdx.y * 128);
    if constexpr (OMODE == 2) {
        if (blockIdx.x == 0 && blockIdx.y == 0 && threadIdx.x == 0) {
            // S2 = sum(exp(log(softmax+1e-20))) = B*H*L exactly
            double kl = (-acc[0] + 512.0 * acc[2] + 65536.0) / 33554432.0;
            of[4194304] = (float)kl;
        }
    }
}

// fused Q+K split projections: z selects planes (A, W, bias, out contiguous)
__global__ __launch_bounds__(256) void k_gemm_qk(
    const bh_t* __restrict__ Abase, const bh_t* __restrict__ Wbase,
    const float* __restrict__ bq, const float* __restrict__ bk,
    bh_t* __restrict__ Obase)
{
    const int z = blockIdx.z;
    const bh_t* AH = Abase + (size_t)z * 2 * PE;
    const bh_t* WH = Wbase + (size_t)z * 2ull * 1024ull * 1024ull;
    bh_t* oh = Obase + (size_t)z * 2 * PE;
    gemm_body<true, 0>(AH, AH + PE, WH, WH + 1024ull*1024ull,
                       z ? bk : bq, oh, oh + PE, nullptr,
                       blockIdx.x * 128, blockIdx.y * 128);
}

// dot_gamma[b,h,l] = Wp2 . leakyrelu(K_head[b,h,l,:] @ Wp1 + bp1) + bp2
__global__ __launch_bounds__(256) void k_prior(
    const bh_t* __restrict__ KH, const bh_t* __restrict__ WP1T,
    const float* __restrict__ bp1, const float* __restrict__ wp2,
    const float* __restrict__ bp2, float* __restrict__ DG)
{
    __shared__ __align__(16) bh_t Kt[64][72];
    __shared__ __align__(16) bh_t Wt[64][72];
    const int lt = blockIdx.x, h = blockIdx.y, b = blockIdx.z;
    const int t = threadIdx.x, lane = t & 63, w = t >> 6;
    const int lr = lane & 15, kg = lane >> 4;
    {
        int r = t >> 2, j0 = (t & 3) * 16;
        const bh_t* src = KH + ((size_t)(b*512 + lt*64 + r)) * 1024 + h*64 + j0;
        *(bh8*)&Kt[r][j0]     = *(const bh8*)src;
        *(bh8*)&Kt[r][j0 + 8] = *(const bh8*)(src + 8);
    }
    __syncthreads();
    bh8 af0 = *(bh8*)&Kt[w*16 + lr][kg * 8];
    bh8 af1 = *(bh8*)&Kt[w*16 + lr][32 + kg * 8];
    float dgp[4] = {0.f, 0.f, 0.f, 0.f};
    for (int dt = 0; dt < 16; dt++) {
        __syncthreads();
        {
            int r = t >> 2, j0 = (t & 3) * 16;
            const bh_t* src = WP1T + (size_t)(dt*64 + r) * 64 + j0;
            *(bh8*)&Wt[r][j0]     = *(const bh8*)src;
            *(bh8*)&Wt[r][j0 + 8] = *(const bh8*)(src + 8);
        }
        __syncthreads();
#pragma unroll
        for (int fn = 0; fn < 4; fn++) {
            bh8 b0 = *(bh8*)&Wt[fn*16 + lr][kg * 8];
            bh8 b1 = *(bh8*)&Wt[fn*16 + lr][32 + kg * 8];
            f32x4 acc = {};
            acc = MFMA_BF16(af0, b0, acc, 0, 0, 0);
            acc = MFMA_BF16(af1, b1, acc, 0, 0, 0);
            int d = dt*64 + fn*16 + lr;
            float bpv = bp1[d], wvv = wp2[d];
#pragma unroll
            for (int r = 0; r < 4; r++) {
                float hv = acc[r] + bpv;
                hv = (hv >= 0.f) ? hv : 0.01f * hv;
                dgp[r] = fmaf(hv, wvv, dgp[r]);
            }
        }
    }
#pragma unroll
    for (int r = 0; r < 4; r++) {
        float v = dgp[r];
        v += __shfl_xor(v, 1); v += __shfl_xor(v, 2);
        v += __shfl_xor(v, 4); v += __shfl_xor(v, 8);
        dgp[r] = v;
    }
    if (lr == 0) {
        float b2 = bp2[0];
        int bh = b * 16 + h;
#pragma unroll
        for (int r = 0; r < 4; r++)
            DG[(size_t)bh*512 + lt*64 + w*16 + kg*4 + r] = dgp[r] + b2;
    }
}

// alpha = softmax_k(dot_gamma); accumulate alpha-only KL terms into acc[2]
__global__ __launch_bounds__(512) void k_alpha(
    const float* __restrict__ DG, float* __restrict__ AL, double* __restrict__ acc)
{
    __shared__ float red[512];
    const int bh = blockIdx.x, t = threadIdx.x;
    float v = DG[(size_t)bh * 512 + t];
    red[t] = v; __syncthreads();
    for (int s = 256; s > 0; s >>= 1) { if (t < s) red[t] = fmaxf(red[t], red[t+s]); __syncthreads(); }
    float m = red[0]; __syncthreads();
    float e = expf(v - m);
    red[t] = e; __syncthreads();
    for (int s = 256; s > 0; s >>= 1) { if (t < s) red[t] += red[t+s]; __syncthreads(); }
    float ssum = red[0]; __syncthreads();
    float a = e / ssum;                 // * BETA_GAMMA (=1)
    AL[(size_t)bh * 512 + t] = a;
    // lg1 + 2*eulergamma
    float t2 = a * 1.8475785103630112f + lgammaf(a + 1e-20f);
    red[t] = t2; __syncthreads();
    for (int s = 256; s > 0; s >>= 1) { if (t < s) red[t] += red[t+s]; __syncthreads(); }
    if (t == 0) atomicAdd(&acc[2], (double)red[0]);
}

// fused stochastic attention: one block per (b,h, 128-row q-chunk), 8 waves.
// pass A: QK split-MFMA + online (M1,Z1) + G chain -> fp16 spill (interleaved)
// pass B: K-restage + 3-MFMA logit recompute + 2-trans logsumexp chain
//         + softmax-2 + PV (Vt LDS)
__global__ __launch_bounds__(512, 3) void k_attn(
    const bh_t* __restrict__ QH, const bh_t* __restrict__ QL,
    const bh_t* __restrict__ KH, const bh_t* __restrict__ KL,
    const bh_t* __restrict__ VT, const float* __restrict__ U,
    const float* __restrict__ AL, bh_t* __restrict__ HOB,
    hf_t* __restrict__ GS, double* __restrict__ acc)
{
    __shared__ __align__(16) bh_t KtH[64][72];
    __shared__ __align__(16) bh_t KtL[64][72];
    __shared__ __align__(16) bh_t Vt[64][72];
    __shared__ __align__(16) bh_t Sl[8][16][72];
    __shared__ float Asm[64];
    __shared__ float red[512];

    const int flat = blockIdx.x;
    const int bh = flat & 127, qc = flat >> 7;   // 4 q-chunks of one bh share an XCD
    const int b = bh >> 4, h = bh & 15;
    const int t = threadIdx.x, w = t >> 6, lane = t & 63;
    const int lr = lane & 15, kg = lane >> 4;
    const int q0 = qc * 128 + w * 16;
    const int sr = t >> 3, sj = (t & 7) * 8;
    const float* Up = U + ((size_t)bh * 512 + q0 + kg * 4) * 512;
    hf_t* GSp = GS + (size_t)flat * 65536 + (size_t)w * 8192;

    bh8 qh[2], ql[2];
    {
        size_t qb = ((size_t)(b * 512) + q0 + lr) * 1024 + h * 64;
        qh[0] = *(const bh8*)(QH + qb + kg * 8);
        qh[1] = *(const bh8*)(QH + qb + 32 + kg * 8);
        ql[0] = *(const bh8*)(QL + qb + kg * 8);
        ql[1] = *(const bh8*)(QL + qb + 32 + kg * 8);
    }
    float C[4];   // per-q-row M1 + lnZ1, carried A -> B

    // ---- pass A: logits (split-bf16 MFMA), G chain + fp16 spill, M1/Z1 ----
    {
        float M1[4], Z1[4];
#pragma unroll
        for (int r = 0; r < 4; r++) { M1[r] = -INFINITY; Z1[r] = 0.f; }

        for (int kt = 0; kt < 8; kt++) {
            __syncthreads();
            {
                size_t src = ((size_t)(b*512 + kt*64 + sr)) * 1024 + h*64 + sj;
                *(bh8*)&KtH[sr][sj] = *(const bh8*)(KH + src);
                *(bh8*)&KtL[sr][sj] = *(const bh8*)(KL + src);
            }
            __syncthreads();
            f32x4 av[4];
#pragma unroll
            for (int fn = 0; fn < 4; fn++) {
                f32x4 a = {};
#pragma unroll
                for (int ks = 0; ks < 2; ks++) {
                    bh8 kb  = *(bh8*)&KtH[fn*16 + lr][ks*32 + kg*8];
                    bh8 kl2 = *(bh8*)&KtL[fn*16 + lr][ks*32 + kg*8];
                    a = MFMA_BF16(qh[ks], kb,  a, 0, 0, 0);
                    a = MFMA_BF16(qh[ks], kl2, a, 0, 0, 0);
                    a = MFMA_BF16(ql[ks], kb,  a, 0, 0, 0);
                }
#pragma unroll
                for (int r = 0; r < 4; r++) a[r] *= 8.0f;   // att / SCALE, SCALE=1/8
                av[fn] = a;
                // Gumbel/lgamma chain fills MFMA latency; spill G fp16.
                int k = kt * 64 + fn * 16 + lr;
                hf4 gh;
#pragma unroll
                for (int r = 0; r < 4; r++) {
                    float u  = Up[(size_t)r * 512 + k];
                    float tt = (1.0f - u) + 1e-20f;
                    float gl = 1e-20f - __logf(tt);
                    float g  = __logf(gl);
                    gh[r] = (hf_t)lgamma_fast(fmaf(2.0f, g, 3.0f)); // 1+1/k+(1/k)*gumbel
                }
                *(hf4*)(GSp + ((size_t)(kt*4 + fn) * 64 + lane) * 4) = gh;
            }
#pragma unroll
            for (int r = 0; r < 4; r++) {
                float mx = fmaxf(fmaxf(av[0][r], av[1][r]), fmaxf(av[2][r], av[3][r]));
                mx = fmaxf(mx, __shfl_xor(mx, 1));
                mx = fmaxf(mx, __shfl_xor(mx, 2));
                mx = fmaxf(mx, __shfl_xor(mx, 4));
                mx = fmaxf(mx, __shfl_xor(mx, 8));
                float nm = fmaxf(M1[r], mx);
                float es = __expf(av[0][r]-nm) + __expf(av[1][r]-nm)
                         + __expf(av[2][r]-nm) + __expf(av[3][r]-nm);
                es += __shfl_xor(es, 1); es += __shfl_xor(es, 2);
                es += __shfl_xor(es, 4); es += __shfl_xor(es, 8);
                Z1[r] = Z1[r] * __expf(M1[r] - nm) + es;
                M1[r] = nm;
            }
        }
#pragma unroll
        for (int r = 0; r < 4; r++) C[r] = M1[r] + logf(Z1[r]);
    }

    // ---- pass B: restage K+V; recompute s; 2-trans chain; softmax-2 + PV --
    float M2[4], Z2[4];
    f32x4 oacc[4] = {};
#pragma unroll
    for (int r = 0; r < 4; r++) { M2[r] = -INFINITY; Z2[r] = 0.f; }
    float S1f = 0.f;
    const float LEPS = 46.0517019f;   // -log(1e-20)

    for (int kt = 0; kt < 8; kt++) {
        __syncthreads();
        {   // stage K hi/lo + V^T tile (all vectorized) + alpha tile
            size_t src = ((size_t)(b*512 + kt*64 + sr)) * 1024 + h*64 + sj;
            *(bh8*)&KtH[sr][sj] = *(const bh8*)(KH + src);
            *(bh8*)&KtL[sr][sj] = *(const bh8*)(KL + src);
            const bh_t* vsrc = VT + ((size_t)bh * 64 + sr) * 512 + kt*64 + sj;
            *(bh8*)&Vt[sr][sj] = *(const bh8*)vsrc;
            if (t < 64) Asm[t] = AL[(size_t)bh * 512 + kt * 64 + t];
        }
        __syncthreads();
        f32x4 wv[4], zq[4];
#pragma unroll
        for (int fn = 0; fn < 4; fn++) {
            f32x4 a = {};
#pragma unroll
            for (int ks = 0; ks < 2; ks++) {
                bh8 kb  = *(bh8*)&KtH[fn*16 + lr][ks*32 + kg*8];
                bh8 kl2 = *(bh8*)&KtL[fn*16 + lr][ks*32 + kg*8];
                a = MFMA_BF16(qh[ks], kb,  a, 0, 0, 0);
                a = MFMA_BF16(qh[ks], kl2, a, 0, 0, 0);
                a = MFMA_BF16(ql[ks], kb,  a, 0, 0, 0);
            }
            hf4 gh = *(const hf4*)(GSp + ((size_t)(kt*4 + fn) * 64 + lane) * 4);
            float alv = Asm[fn * 16 + lr];
#pragma unroll
            for (int r = 0; r < 4; r++) {
                float s  = fmaf(a[r], 8.0f, -C[r]);       // logit - (M1+lnZ1)
                // lp = logsumexp(s, -46.0517) = m0 + log1p(z) (EXACT identity)
                float m0 = fmaxf(s, -LEPS);
                float d  = fabsf(s + LEPS);
                float z  = __expf(-d);
                zq[fn][r] = z;
                // S1: log1p(z) ~= z - z^2/2  (dKL ~ 1e-6)
                S1f = fmaf(alv, m0 + z * fmaf(-0.5f, z, 1.0f), S1f);
                wv[fn][r] = m0 - (float)gh[r];            // quasi-wv (true = +log1p(z))
            }
        }
#pragma unroll
        for (int r = 0; r < 4; r++) {
            float mx = fmaxf(fmaxf(wv[0][r], wv[1][r]), fmaxf(wv[2][r], wv[3][r]));
            mx = fmaxf(mx, __shfl_xor(mx, 1));
            mx = fmaxf(mx, __shfl_xor(mx, 2));
            mx = fmaxf(mx, __shfl_xor(mx, 4));
            mx = fmaxf(mx, __shfl_xor(mx, 8));
            float nm = fmaxf(M2[r], mx + 0.6931472f);    // bound >= all true wv
            float sc = __expf(M2[r] - nm);               // exp(-inf)=0, exp(0)=1
            float zs = 0.f;
#pragma unroll
            for (int fn = 0; fn < 4; fn++) {
                // exp(true_wv - nm) = exp(quasi - nm) * (1+z)  (exact)
                float sv = __expf(wv[fn][r] - nm) * (1.0f + zq[fn][r]);
                zs += sv;
                Sl[w][kg * 4 + r][fn * 16 + lr] = (bh_t)sv;
            }
            zs += __shfl_xor(zs, 1); zs += __shfl_xor(zs, 2);
            zs += __shfl_xor(zs, 4); zs += __shfl_xor(zs, 8);
            Z2[r] = fmaf(Z2[r], sc, zs);
            M2[r] = nm;
#pragma unroll
            for (int fo = 0; fo < 4; fo++) oacc[fo][r] *= sc;
        }
        // no extra barrier: Sl slice is per-wave (program-ordered); Vt/KtH
        // staged behind barrier and only rewritten after next loop-top barrier.
        bh8 sa0 = *(bh8*)&Sl[w][lr][kg*8];
        bh8 sa1 = *(bh8*)&Sl[w][lr][32 + kg*8];
#pragma unroll
        for (int fo = 0; fo < 4; fo++) {
            bh8 v0 = *(bh8*)&Vt[fo*16 + lr][kg*8];
            bh8 v1 = *(bh8*)&Vt[fo*16 + lr][32 + kg*8];
            oacc[fo] = MFMA_BF16(sa0, v0, oacc[fo], 0, 0, 0);
            oacc[fo] = MFMA_BF16(sa1, v1, oacc[fo], 0, 0, 0);
        }
    }
    float rz[4];
#pragma unroll
    for (int r = 0; r < 4; r++) rz[r] = 1.0f / Z2[r];
    // head output (bf16): HO[b, q, h*64+dv]
#pragma unroll
    for (int fo = 0; fo < 4; fo++) {
#pragma unroll
        for (int r = 0; r < 4; r++) {
            int q = q0 + kg * 4 + r;
            int dv = fo * 16 + lr;
            HOB[((size_t)(b * 512 + q)) * 1024 + h * 64 + dv] = (bh_t)(oacc[fo][r] * rz[r]);
        }
    }
    red[t] = S1f; __syncthreads();
    for (int s = 256; s > 0; s >>= 1) { if (t < s) red[t] += red[t+s]; __syncthreads(); }
    if (t == 0) atomicAdd(&acc[0], (double)red[0]);
}

// ---------------------------------------------------------------------------
extern "C" void kernel_launch(void* const* d_in, const int* in_sizes, int n_in,
                              void* d_out, int out_size, void* d_ws, size_t ws_size,
                              hipStream_t stream)
{
    (void)in_sizes; (void)n_in; (void)d_ws; (void)ws_size; (void)out_size;
    const float* queries = (const float*)d_in[0];
    const float* keys    = (const float*)d_in[1];
    const float* values  = (const float*)d_in[2];
    const float* unif    = (const float*)d_in[3];
    const float* Wq = (const float*)d_in[4];  const float* bq = (const float*)d_in[5];
    const float* Wk = (const float*)d_in[6];  const float* bk = (const float*)d_in[7];
    const float* Wv = (const float*)d_in[8];  const float* bv = (const float*)d_in[9];
    const float* Wo = (const float*)d_in[10]; const float* bo = (const float*)d_in[11];
    const float* Wp1 = (const float*)d_in[12]; const float* bp1 = (const float*)d_in[13];
    const float* Wp2 = (const float*)d_in[14]; const float* bp2 = (const float*)d_in[15];

    unsigned char* ws = nullptr;
    hipGetSymbolAddress((void**)&ws, HIP_SYMBOL(g_ws));

    bh_t* QHI = (bh_t*)(ws + O_QHI); bh_t* QLO = (bh_t*)(ws + O_QLO);
    bh_t* KHI = (bh_t*)(ws + O_KHI); bh_t* KLO = (bh_t*)(ws + O_KLO);
    bh_t* VTp = (bh_t*)(ws + O_VT);
    bh_t* WQH = (bh_t*)(ws + O_WQH);
    bh_t* WVH = (bh_t*)(ws + O_WVH); bh_t* WVL = (bh_t*)(ws + O_WVL);
    bh_t* WOH = (bh_t*)(ws + O_WOH); bh_t* WOL = (bh_t*)(ws + O_WOL);
    bh_t* WP1H = (bh_t*)(ws + O_WP1H); bh_t* WP1L = (bh_t*)(ws + O_WP1L);
    float* DG    = (float*)(ws + O_DG);
    float* ALPHA = (float*)(ws + O_ALPHA);
    bh_t*  HOB   = (bh_t*)(ws + O_HO);
    hf_t*  GS    = (hf_t*)(ws + O_GS);
    double* ACC  = (double*)(ws + O_ACC);
    bh_t*  AQH   = (bh_t*)(ws + O_AQH);
    bh_t*  AVH   = AQH + 4 * PE;
    float* outF  = (float*)d_out;

    // weight transposes (+ ACC zeroing) and activation pre-split
    k_transpose_split4<<<dim3(16,16,4), 256, 0, stream>>>(Wq, Wk, Wv, Wo, WQH, ACC);
    k_transpose_split<<<dim3(16,1), 256, 0, stream>>>(Wp1, WP1H, WP1L, 64, 1024);
    k_splitA<<<dim3(2048,3), 256, 0, stream>>>(queries, keys, values, AQH);

    // Q and K split projections fused (z=2); V projection writes VT directly
    k_gemm_qk<<<dim3(8,32,2), 256, 0, stream>>>(AQH, WQH, bq, bk, QHI);
    k_gemm<3><<<dim3(8,32), 256, 0, stream>>>(AVH, WVH, WVL, bv, VTp, nullptr, nullptr);

    k_prior<<<dim3(8,16,8), 256, 0, stream>>>(KHI, WP1H, bp1, Wp2, bp2, DG);
    k_alpha<<<128, 512, 0, stream>>>(DG, ALPHA, ACC);

    k_attn<<<512, 512, 0, stream>>>(QHI, QLO, KHI, KLO, VTp, unif, ALPHA, HOB, GS, ACC);

    // output GEMM (f32) + KL finalization folded into its epilogue
    k_gemm<2><<<dim3(8,32), 256, 0, stream>>>(HOB, WOH, WOL, bo, nullptr, outF, ACC);
}